// Round 4
// baseline (1098.536 us; speedup 1.0000x reference)
//
#include <hip/hip_runtime.h>
#include <hip/hip_bf16.h>
#include <math.h>

#define B_N 32768
#define COORD 64
#define DG 2048
#define CA 256
#define K_ACT 81
#define SETTLE_STEPS 5
#define GAIN 0.7f
#define LN_EPS 1e-5f
#define COS_EPS 1e-8f

__device__ __forceinline__ float wave_sum(float v) {
#pragma unroll
  for (int d = 1; d < 64; d <<= 1) v += __shfl_xor(v, d);
  return v;
}

__device__ __forceinline__ float dot4(float4 a, float4 b) {
  return a.x * b.x + a.y * b.y + a.z * b.z + a.w * b.w;
}

__device__ __forceinline__ void fma4(float4& a, float s, float4 w) {
  a.x += s * w.x; a.y += s * w.y; a.z += s * w.z; a.w += s * w.w;
}

// tanh(x) = 1 - 2/(e^{2x}+1); abs err ~1e-6, exact limits at +-inf.
__device__ __forceinline__ float fast_tanh(float x) {
  float e = __expf(2.0f * x);
  return 1.0f - 2.0f / (e + 1.0f);
}

__device__ __forceinline__ unsigned int okey(float f) {
  unsigned int u = __float_as_uint(f);
  return (u & 0x80000000u) ? ~u : (u | 0x80000000u);
}

// ---- column sums of coords (for buf) ----
__global__ void colsum_kernel(const float* __restrict__ coords,
                              float* __restrict__ colsum) {
  int tid = threadIdx.x;
  int col = tid & 63;
  int rg = tid >> 6;
  float s = 0.f;
  int base = blockIdx.x * 128;
#pragma unroll 4
  for (int i = 0; i < 32; ++i) {
    int r = base + rg + i * 4;
    s += coords[r * COORD + col];
  }
  __shared__ float sh[256];
  sh[tid] = s;
  __syncthreads();
  if (tid < 64) {
    float t = sh[tid] + sh[tid + 64] + sh[tid + 128] + sh[tid + 192];
    atomicAdd(&colsum[tid], t);
  }
}

// ---- generic transpose: T[c*R + r] = S[r*C + c] ----
__global__ void transpose_any(const float* __restrict__ S,
                              float* __restrict__ T, int R, int C) {
  int idx = blockIdx.x * 256 + threadIdx.x;
  if (idx < R * C) {
    int r = idx / C, c = idx - r * C;
    T[c * R + r] = S[r * C + c];
  }
}

// ---- fused-weight precompute: FT[in][out] = dot(A[out,:], BT[in,:]) (K=256)
// and (block in==0) cvec[out] = dot(A[out,:], bvec). F = A @ B, consumed as
// y = x @ F^T via FT layout identical to W_recT's [in][out].
__global__ void fuse_mm(const float* __restrict__ A, const float* __restrict__ BT,
                        const float* __restrict__ bvec, float* __restrict__ FT,
                        float* __restrict__ cvec) {
  __shared__ float brow[256];
  int in = blockIdx.x, out = threadIdx.x;
  brow[out] = BT[in * 256 + out];
  __syncthreads();
  const float* arow = A + out * 256;
  float acc = 0.f;
#pragma unroll 4
  for (int k = 0; k < 256; ++k) acc += arow[k] * brow[k];
  FT[in * 256 + out] = acc;
  if (in == 0) {
    float b = 0.f;
#pragma unroll 4
    for (int k = 0; k < 256; ++k) b += arow[k] * bvec[k];
    cvec[out] = b;
  }
}

// ============ mega1: EC-LN -> proj(+LN) -> radix top-81 -> cue ============
__global__ __launch_bounds__(512, 4) void mega1(
    const float* __restrict__ coords, const float* __restrict__ colsum,
    const float* __restrict__ ec_gamma, const float* __restrict__ ec_beta,
    const float* __restrict__ W_ppT, const float* __restrict__ b_pp,
    const float* __restrict__ dg_gamma, const float* __restrict__ dg_beta,
    const float* __restrict__ WmT, float* __restrict__ cue_g) {
  __shared__ __align__(16) float proj_s[8][DG];
  __shared__ __align__(16) float ec_s[8][COORD];
  __shared__ unsigned int hist[8][256];
  __shared__ float psum_s[8][8], psq_s[8][8];
  __shared__ int sel_s[8][88];

  const int w = threadIdx.x >> 6;
  const int l = threadIdx.x & 63;
  const int row0 = blockIdx.x * 8;

  // ---- A: EC layernorm (wave w -> row w) ----
  {
    int row = row0 + w;
    float x = coords[row * COORD + l] + (0.05f / (float)B_N) * colsum[l];
    float mu = wave_sum(x) * (1.f / 64.f);
    float d = x - mu;
    float var = wave_sum(d * d) * (1.f / 64.f);
    ec_s[w][l] = d * rsqrtf(var + LN_EPS) * ec_gamma[l] + ec_beta[l];
  }
  __syncthreads();

  // ---- B: proj chunk for all 8 rows ----
  {
    float4 acc[8];
#pragma unroll
    for (int r = 0; r < 8; ++r) acc[r] = make_float4(0.f, 0.f, 0.f, 0.f);
    const float4* wp4 = reinterpret_cast<const float4*>(W_ppT);
    const int cbase = 64 * w + l;
    for (int kg = 0; kg < 16; ++kg) {
      float4 w40 = wp4[(4 * kg + 0) * 512 + cbase];
      float4 w41 = wp4[(4 * kg + 1) * 512 + cbase];
      float4 w42 = wp4[(4 * kg + 2) * 512 + cbase];
      float4 w43 = wp4[(4 * kg + 3) * 512 + cbase];
#pragma unroll
      for (int r = 0; r < 8; ++r) {
        float4 e4 = reinterpret_cast<const float4*>(ec_s[r])[kg];
        fma4(acc[r], e4.x, w40);
        fma4(acc[r], e4.y, w41);
        fma4(acc[r], e4.z, w42);
        fma4(acc[r], e4.w, w43);
      }
    }
    float4 bp = reinterpret_cast<const float4*>(b_pp)[cbase];
#pragma unroll
    for (int r = 0; r < 8; ++r) {
      float4 h;
      h.x = fmaxf(acc[r].x + bp.x, 0.f);
      h.y = fmaxf(acc[r].y + bp.y, 0.f);
      h.z = fmaxf(acc[r].z + bp.z, 0.f);
      h.w = fmaxf(acc[r].w + bp.w, 0.f);
      reinterpret_cast<float4*>(proj_s[r])[cbase] = h;
      float ps = wave_sum(h.x + h.y + h.z + h.w);
      float pq = wave_sum(dot4(h, h));
      if (l == 0) { psum_s[w][r] = ps; psq_s[w][r] = pq; }
    }
  }
  __syncthreads();

  // ---- C: wave w -> row w: LN + radix top-81 + cue ----
  float mu2, rs2;
  {
    float s = 0.f, q = 0.f;
#pragma unroll
    for (int w2 = 0; w2 < 8; ++w2) { s += psum_s[w2][w]; q += psq_s[w2][w]; }
    mu2 = s * (1.f / (float)DG);
    float var = q * (1.f / (float)DG) - mu2 * mu2;
    rs2 = rsqrtf(var + LN_EPS);
  }
  unsigned int key[32];
#pragma unroll 4
  for (int i = 0; i < 32; ++i) {
    int j = i * 64 + l;
    float v = (proj_s[w][j] - mu2) * rs2 * dg_gamma[j] + dg_beta[j];
    proj_s[w][j] = v;
    key[i] = okey(v);
  }

  unsigned int prefix = 0, rem = K_ACT;
#pragma unroll 1
  for (int pass = 0; pass < 4; ++pass) {
    int sh = 24 - 8 * pass;
#pragma unroll
    for (int b = l; b < 256; b += 64) hist[w][b] = 0;
#pragma unroll 4
    for (int i = 0; i < 32; ++i) {
      unsigned int k = key[i];
      bool ok = (pass == 0) || ((k >> (sh + 8)) == prefix);
      if (ok) atomicAdd(&hist[w][(k >> sh) & 255u], 1u);
    }
    unsigned int h0 = hist[w][4 * l + 0], h1 = hist[w][4 * l + 1];
    unsigned int h2 = hist[w][4 * l + 2], h3 = hist[w][4 * l + 3];
    unsigned int own = h0 + h1 + h2 + h3;
    unsigned int inc = own;
#pragma unroll
    for (int d = 1; d < 64; d <<= 1) {
      unsigned int v = __shfl_down(inc, d);
      if (l + d < 64) inc += v;
    }
    unsigned int cnt = inc - own;
    unsigned int pk = 0;
    {
      unsigned int hb;
      hb = h3; if (cnt < rem && rem <= cnt + hb) pk = ((rem - cnt) << 8) | (unsigned)(4 * l + 3); cnt += hb;
      hb = h2; if (cnt < rem && rem <= cnt + hb) pk = ((rem - cnt) << 8) | (unsigned)(4 * l + 2); cnt += hb;
      hb = h1; if (cnt < rem && rem <= cnt + hb) pk = ((rem - cnt) << 8) | (unsigned)(4 * l + 1); cnt += hb;
      hb = h0; if (cnt < rem && rem <= cnt + hb) pk = ((rem - cnt) << 8) | (unsigned)(4 * l + 0); cnt += hb;
    }
#pragma unroll
    for (int d = 1; d < 64; d <<= 1) pk |= __shfl_xor(pk, d);
    prefix = (prefix << 8) | (pk & 255u);
    rem = pk >> 8;
  }
  const unsigned int Tkey = prefix;
  const unsigned int rem_final = rem;

  const unsigned long long below = (1ull << l) - 1ull;
  int basec = 0;
  unsigned int eq_seen = 0;
  for (int i = 0; i < 32; ++i) {
    int j = i * 64 + l;
    unsigned int k = key[i];
    bool gt = k > Tkey;
    bool eq = (k == Tkey);
    unsigned long long em = __ballot(eq);
    unsigned int eq_before = eq_seen + (unsigned)__popcll(em & below);
    bool sel = gt || (eq && (eq_before < rem_final));
    unsigned long long sm = __ballot(sel);
    int pos = basec + (int)__popcll(sm & below);
    if (sel) sel_s[w][pos] = j;
    basec += (int)__popcll(sm);
    eq_seen += (unsigned)__popcll(em);
  }

  float4 c4 = make_float4(0.f, 0.f, 0.f, 0.f);
  const float4* wm4 = reinterpret_cast<const float4*>(WmT);
  for (int k = 0; k < K_ACT; ++k) {
    int j = sel_s[w][k];
    float v = proj_s[w][j];
    fma4(c4, v, wm4[j * 64 + l]);
  }
  reinterpret_cast<float4*>(cue_g)[(size_t)(row0 + w) * 64 + l] = c4;
}

// ============ mega2: settle + fused epilogue. 4 waves, 8 rows/wave ========
// s_proj = state@F1^T+c1, d_proj = ec@F2^T+c2, out = tanh(g*(ec@F4^T+c4) +
// (1-g)*(state@F3^T+c3) + b_og). ca1/direct/combined never materialize.
__global__ __launch_bounds__(256, 4) void mega2(
    const float* __restrict__ coords, const float* __restrict__ colsum,
    const float* __restrict__ ec_gamma, const float* __restrict__ ec_beta,
    const float* __restrict__ cue_g, const float* __restrict__ W_recT,
    const float* __restrict__ F1T, const float* __restrict__ c1,
    const float* __restrict__ F2T, const float* __restrict__ c2,
    const float* __restrict__ F3T, const float* __restrict__ c3,
    const float* __restrict__ F4T, const float* __restrict__ c4v,
    const float* __restrict__ b_og, float* __restrict__ out) {
  __shared__ __align__(16) float st_s[32][CA];    // 32 KB
  __shared__ __align__(16) float ec_s[32][COORD]; // 8 KB

  const int w = threadIdx.x >> 6;
  const int l = threadIdx.x & 63;
  const int row0 = blockIdx.x * 32 + w * 8;

  // ---- EC layernorm for this wave's 8 rows ----
#pragma unroll 1
  for (int r = 0; r < 8; ++r) {
    int row = row0 + r;
    float x = coords[row * COORD + l] + (0.05f / (float)B_N) * colsum[l];
    float mu = wave_sum(x) * (1.f / 64.f);
    float d = x - mu;
    float var = wave_sum(d * d) * (1.f / 64.f);
    ec_s[w * 8 + r][l] = d * rsqrtf(var + LN_EPS) * ec_gamma[l] + ec_beta[l];
  }

  // ---- load cue, init state ----
  float4 cu[8];
#pragma unroll
  for (int r = 0; r < 8; ++r) {
    cu[r] = reinterpret_cast<const float4*>(cue_g)[(size_t)(row0 + r) * 64 + l];
    reinterpret_cast<float4*>(st_s[w * 8 + r])[l] = cu[r];
  }

  float4 acc[8];

  // ---- settle x5: state = tanh(0.7*(state @ W_rec^T) + 0.3*cue) ----
  {
    const float4* wr4 = reinterpret_cast<const float4*>(W_recT);
#pragma unroll 1
    for (int it = 0; it < SETTLE_STEPS; ++it) {
#pragma unroll
      for (int r = 0; r < 8; ++r) acc[r] = make_float4(0.f, 0.f, 0.f, 0.f);
#pragma unroll 2
      for (int jg = 0; jg < 64; ++jg) {
        float4 w40 = wr4[(4 * jg + 0) * 64 + l];
        float4 w41 = wr4[(4 * jg + 1) * 64 + l];
        float4 w42 = wr4[(4 * jg + 2) * 64 + l];
        float4 w43 = wr4[(4 * jg + 3) * 64 + l];
#pragma unroll
        for (int r = 0; r < 8; ++r) {
          float4 s4 = reinterpret_cast<const float4*>(st_s[w * 8 + r])[jg];
          fma4(acc[r], s4.x, w40);
          fma4(acc[r], s4.y, w41);
          fma4(acc[r], s4.z, w42);
          fma4(acc[r], s4.w, w43);
        }
      }
#pragma unroll
      for (int r = 0; r < 8; ++r) {
        float4 ns;
        ns.x = fast_tanh(GAIN * acc[r].x + (1.f - GAIN) * cu[r].x);
        ns.y = fast_tanh(GAIN * acc[r].y + (1.f - GAIN) * cu[r].y);
        ns.z = fast_tanh(GAIN * acc[r].z + (1.f - GAIN) * cu[r].z);
        ns.w = fast_tanh(GAIN * acc[r].w + (1.f - GAIN) * cu[r].w);
        reinterpret_cast<float4*>(st_s[w * 8 + r])[l] = ns;
      }
    }
  }

  // ---- d_proj = ec @ F2^T + c2 ----
  float4 dpr[8];
  {
    const float4* f4 = reinterpret_cast<const float4*>(F2T);
#pragma unroll
    for (int r = 0; r < 8; ++r) dpr[r] = make_float4(0.f, 0.f, 0.f, 0.f);
#pragma unroll 2
    for (int kg = 0; kg < 16; ++kg) {
      float4 w40 = f4[(4 * kg + 0) * 64 + l];
      float4 w41 = f4[(4 * kg + 1) * 64 + l];
      float4 w42 = f4[(4 * kg + 2) * 64 + l];
      float4 w43 = f4[(4 * kg + 3) * 64 + l];
#pragma unroll
      for (int r = 0; r < 8; ++r) {
        float4 e4 = reinterpret_cast<const float4*>(ec_s[w * 8 + r])[kg];
        fma4(dpr[r], e4.x, w40);
        fma4(dpr[r], e4.y, w41);
        fma4(dpr[r], e4.z, w42);
        fma4(dpr[r], e4.w, w43);
      }
    }
    float4 cb = reinterpret_cast<const float4*>(c2)[l];
#pragma unroll
    for (int r = 0; r < 8; ++r) {
      dpr[r].x += cb.x; dpr[r].y += cb.y; dpr[r].z += cb.z; dpr[r].w += cb.w;
    }
  }

  // ---- s_proj = state @ F1^T + c1 ----
  {
    const float4* f4 = reinterpret_cast<const float4*>(F1T);
#pragma unroll
    for (int r = 0; r < 8; ++r) acc[r] = make_float4(0.f, 0.f, 0.f, 0.f);
#pragma unroll 2
    for (int jg = 0; jg < 64; ++jg) {
      float4 w40 = f4[(4 * jg + 0) * 64 + l];
      float4 w41 = f4[(4 * jg + 1) * 64 + l];
      float4 w42 = f4[(4 * jg + 2) * 64 + l];
      float4 w43 = f4[(4 * jg + 3) * 64 + l];
#pragma unroll
      for (int r = 0; r < 8; ++r) {
        float4 s4 = reinterpret_cast<const float4*>(st_s[w * 8 + r])[jg];
        fma4(acc[r], s4.x, w40);
        fma4(acc[r], s4.y, w41);
        fma4(acc[r], s4.z, w42);
        fma4(acc[r], s4.w, w43);
      }
    }
    float4 cb = reinterpret_cast<const float4*>(c1)[l];
#pragma unroll
    for (int r = 0; r < 8; ++r) {
      acc[r].x += cb.x; acc[r].y += cb.y; acc[r].z += cb.z; acc[r].w += cb.w;
    }
  }

  // ---- novelty gate per row ----
  float nov[8];
#pragma unroll 1
  for (int r = 0; r < 8; ++r) {
    float sd = wave_sum(dot4(acc[r], dpr[r]));
    float sn = wave_sum(dot4(acc[r], acc[r]));
    float dn = wave_sum(dot4(dpr[r], dpr[r]));
    float s_n = fmaxf(sqrtf(sn), COS_EPS);
    float d_n = fmaxf(sqrtf(dn), COS_EPS);
    nov[r] = fminf(fmaxf(1.f - sd / (s_n * d_n), 0.f), 1.f);
    if (l == 0) out[(size_t)B_N * CA + (row0 + r)] = nov[r];
  }

  // ---- o2 = ec @ F4^T + c4 (into dpr) ----
  {
    const float4* f4 = reinterpret_cast<const float4*>(F4T);
#pragma unroll
    for (int r = 0; r < 8; ++r) dpr[r] = make_float4(0.f, 0.f, 0.f, 0.f);
#pragma unroll 2
    for (int kg = 0; kg < 16; ++kg) {
      float4 w40 = f4[(4 * kg + 0) * 64 + l];
      float4 w41 = f4[(4 * kg + 1) * 64 + l];
      float4 w42 = f4[(4 * kg + 2) * 64 + l];
      float4 w43 = f4[(4 * kg + 3) * 64 + l];
#pragma unroll
      for (int r = 0; r < 8; ++r) {
        float4 e4 = reinterpret_cast<const float4*>(ec_s[w * 8 + r])[kg];
        fma4(dpr[r], e4.x, w40);
        fma4(dpr[r], e4.y, w41);
        fma4(dpr[r], e4.z, w42);
        fma4(dpr[r], e4.w, w43);
      }
    }
    float4 cb = reinterpret_cast<const float4*>(c4v)[l];
#pragma unroll
    for (int r = 0; r < 8; ++r) {
      dpr[r].x += cb.x; dpr[r].y += cb.y; dpr[r].z += cb.z; dpr[r].w += cb.w;
    }
  }

  // ---- o1 = state @ F3^T + c3; out = tanh(g*o2 + (1-g)*o1 + b_og) ----
  {
    const float4* f4 = reinterpret_cast<const float4*>(F3T);
#pragma unroll
    for (int r = 0; r < 8; ++r) acc[r] = make_float4(0.f, 0.f, 0.f, 0.f);
#pragma unroll 2
    for (int jg = 0; jg < 64; ++jg) {
      float4 w40 = f4[(4 * jg + 0) * 64 + l];
      float4 w41 = f4[(4 * jg + 1) * 64 + l];
      float4 w42 = f4[(4 * jg + 2) * 64 + l];
      float4 w43 = f4[(4 * jg + 3) * 64 + l];
#pragma unroll
      for (int r = 0; r < 8; ++r) {
        float4 s4 = reinterpret_cast<const float4*>(st_s[w * 8 + r])[jg];
        fma4(acc[r], s4.x, w40);
        fma4(acc[r], s4.y, w41);
        fma4(acc[r], s4.z, w42);
        fma4(acc[r], s4.w, w43);
      }
    }
    float4 cc = reinterpret_cast<const float4*>(c3)[l];
    float4 bo = reinterpret_cast<const float4*>(b_og)[l];
#pragma unroll
    for (int r = 0; r < 8; ++r) {
      float g = nov[r], h = 1.f - nov[r];
      float4 o;
      o.x = fast_tanh(g * dpr[r].x + h * (acc[r].x + cc.x) + bo.x);
      o.y = fast_tanh(g * dpr[r].y + h * (acc[r].y + cc.y) + bo.y);
      o.z = fast_tanh(g * dpr[r].z + h * (acc[r].z + cc.z) + bo.z);
      o.w = fast_tanh(g * dpr[r].w + h * (acc[r].w + cc.w) + bo.w);
      reinterpret_cast<float4*>(out)[(size_t)(row0 + r) * 64 + l] = o;
    }
  }
}

extern "C" void kernel_launch(void* const* d_in, const int* in_sizes, int n_in,
                              void* d_out, int out_size, void* d_ws,
                              size_t ws_size, hipStream_t stream) {
  const float* coords = (const float*)d_in[0];
  const float* ec_gamma = (const float*)d_in[1];
  const float* ec_beta = (const float*)d_in[2];
  const float* W_pp = (const float*)d_in[3];
  const float* b_pp = (const float*)d_in[4];
  const float* dg_gamma = (const float*)d_in[5];
  const float* dg_beta = (const float*)d_in[6];
  const float* W_mossy = (const float*)d_in[7];
  const float* W_rec = (const float*)d_in[8];
  const float* W_sc = (const float*)d_in[9];
  const float* b_sc = (const float*)d_in[10];
  const float* W_ta = (const float*)d_in[11];
  const float* b_ta = (const float*)d_in[12];
  const float* W_cs = (const float*)d_in[13];
  const float* W_cd = (const float*)d_in[14];
  const float* W_og = (const float*)d_in[15];
  const float* b_og = (const float*)d_in[16];
  float* out = (float*)d_out;

  float* ws = (float*)d_ws;
  float* colsum = ws;                        // 64
  float* WmT    = colsum + 64;               // 2048*256
  float* W_ppT  = WmT + 2048 * 256;          // 64*2048
  float* W_recT = W_ppT + 64 * 2048;         // 256*256
  float* W_scT  = W_recT + 256 * 256;        // 256*256
  float* W_taT  = W_scT + 256 * 256;         // 64*256
  float* F1T    = W_taT + 64 * 256;          // 256*256  (W_cs@W_sc)^T-layout
  float* F2T    = F1T + 256 * 256;           // 64*256   (W_cd@W_ta)
  float* F3T    = F2T + 64 * 256;            // 256*256  (W_og@W_sc)
  float* F4T    = F3T + 256 * 256;           // 64*256   (W_og@W_ta)
  float* c1     = F4T + 64 * 256;            // 256
  float* c2     = c1 + 256;                  // 256
  float* c3     = c2 + 256;                  // 256
  float* c4     = c3 + 256;                  // 256
  float* cue_g  = c4 + 256;                  // 32768*256

  hipMemsetAsync(colsum, 0, COORD * sizeof(float), stream);
  colsum_kernel<<<256, 256, 0, stream>>>(coords, colsum);
  transpose_any<<<(256 * 2048 + 255) / 256, 256, 0, stream>>>(W_mossy, WmT, 256, 2048);
  transpose_any<<<(2048 * 64 + 255) / 256, 256, 0, stream>>>(W_pp, W_ppT, 2048, 64);
  transpose_any<<<(256 * 256 + 255) / 256, 256, 0, stream>>>(W_rec, W_recT, 256, 256);
  transpose_any<<<(256 * 256 + 255) / 256, 256, 0, stream>>>(W_sc, W_scT, 256, 256);
  transpose_any<<<(256 * 64 + 255) / 256, 256, 0, stream>>>(W_ta, W_taT, 256, 64);

  // fused epilogue weights (consume W_scT/W_taT)
  fuse_mm<<<256, 256, 0, stream>>>(W_cs, W_scT, b_sc, F1T, c1);
  fuse_mm<<<64, 256, 0, stream>>>(W_cd, W_taT, b_ta, F2T, c2);
  fuse_mm<<<256, 256, 0, stream>>>(W_og, W_scT, b_sc, F3T, c3);
  fuse_mm<<<64, 256, 0, stream>>>(W_og, W_taT, b_ta, F4T, c4);

  mega1<<<B_N / 8, 512, 0, stream>>>(coords, colsum, ec_gamma, ec_beta, W_ppT,
                                     b_pp, dg_gamma, dg_beta, WmT, cue_g);
  mega2<<<B_N / 32, 256, 0, stream>>>(coords, colsum, ec_gamma, ec_beta, cue_g,
                                      W_recT, F1T, c1, F2T, c2, F3T, c3, F4T,
                                      c4, b_og, out);
}